// Round 3
// baseline (48.361 us; speedup 1.0000x reference)
//
#include <hip/hip_runtime.h>
#include <hip/hip_bf16.h>
#include <stdint.h>

#define N_ROWS 8192
#define DIM 256
#define NUM_CLASSES 32
#define NB 32                    // 8192 / 256 tiles per side
#define NWG (NB * (NB + 1) / 2)  // 528 triangular blocks

typedef __attribute__((ext_vector_type(4))) float f32x4;
typedef __attribute__((ext_vector_type(8))) short bf16x8;

static __device__ inline unsigned short f2bf(float f) {
  union { float f; unsigned u; } v; v.f = f;
  unsigned r = v.u + 0x7FFFu + ((v.u >> 16) & 1u);
  return (unsigned short)(r >> 16);
}

static __device__ inline void async_copy16(const void* g, void* l) {
  __builtin_amdgcn_global_load_lds(
      (const __attribute__((address_space(1))) unsigned int*)g,
      (__attribute__((address_space(3))) unsigned int*)l, 16, 0, 0);
}

// ---------------------------------------------------------------------------
// Kernel 1: L2-normalize rows, write bf16. One wave per row, 4 rows/block.
// ---------------------------------------------------------------------------
__global__ __launch_bounds__(256)
void normalize_kernel(const float* __restrict__ emb, unsigned short* __restrict__ en) {
  const int row = blockIdx.x * 4 + (threadIdx.x >> 6);
  const int lane = threadIdx.x & 63;
  const float4 v = reinterpret_cast<const float4*>(emb + (size_t)row * DIM)[lane];
  float s = v.x * v.x + v.y * v.y + v.z * v.z + v.w * v.w;
  #pragma unroll
  for (int o = 32; o; o >>= 1) s += __shfl_xor(s, o);
  const float inv = 1.0f / sqrtf(s);
  ushort4 o4;
  o4.x = f2bf(v.x * inv);
  o4.y = f2bf(v.y * inv);
  o4.z = f2bf(v.z * inv);
  o4.w = f2bf(v.w * inv);
  reinterpret_cast<ushort4*>(en + (size_t)row * DIM)[lane] = o4;
}

// ---------------------------------------------------------------------------
// Kernel 2: fused sim = A·A^T + masked loss partial, 256x256 tile, 8 waves,
// BK=64, double-buffered LDS, raw-barrier 4-phase schedule, batch prefetch
// (vmcnt(0) lands a full K-step after issue -> stall-free), XOR-swizzled LDS.
// ---------------------------------------------------------------------------
__global__ __launch_bounds__(512, 2)
void sim_loss_kernel(const unsigned short* __restrict__ en,
                     const int* __restrict__ labels,
                     float2* __restrict__ parts) {
  // XCD-chunked bijective swizzle (528 % 8 == 0 -> chunks of 66)
  const int orig = blockIdx.x;
  const int p = (orig & 7) * (NWG / 8) + (orig >> 3);

  // triangular decode: cum(bi) = bi*(65-bi)/2
  int bi = (int)((65.0f - sqrtf(4225.0f - 8.0f * (float)p)) * 0.5f);
  while ((bi + 1) * (64 - bi) / 2 <= p) ++bi;
  while (bi * (65 - bi) / 2 > p) --bi;
  const int bj = bi + (p - bi * (65 - bi) / 2);

  __shared__ __align__(16) short lA[2 * 256 * 64];  // 64 KB (2 bufs)
  __shared__ __align__(16) short lB[2 * 256 * 64];  // 64 KB
  __shared__ int labA_s[256];
  __shared__ int labB_s[256];
  __shared__ float red[16];

  const int t = threadIdx.x;
  const int lane = t & 63;
  const int wid = t >> 6;
  const int rowA0 = bi * 256, rowB0 = bj * 256;

  // staging per-thread constants (linear LDS dest, inverse-swizzled source)
  const int r0 = t >> 3;                        // staged row within 64-row strip
  const int cb = (((t & 7) ^ (r0 & 7)) << 4);   // swizzled source col byte
  // fragment-read per-lane constants
  const int r15 = lane & 15;
  const int kq = (lane >> 4) << 4;
  const int sw = (r15 & 7) << 4;
  const int wm = (wid >> 2) * 128;  // wave row base (2 M-waves)
  const int wn = (wid & 3) * 64;    // wave col base (4 N-waves)

  if (t < 256) labA_s[t] = labels[rowA0 + t];
  else         labB_s[t - 256] = labels[rowB0 + (t - 256)];

  f32x4 accf[8][4];
  #pragma unroll
  for (int i = 0; i < 8; ++i)
    #pragma unroll
    for (int j = 0; j < 4; ++j) accf[i][j] = (f32x4){0.f, 0.f, 0.f, 0.f};

  const char* enb = (const char*)en;

// stage all 4 half-tiles (A rows 0-127/128-255, B same) of K-step KT into buf B_
#define STAGE_BATCH(B_, KT)                                                    \
  {                                                                            \
    const int kb = (KT) * 128;                                                 \
    _Pragma("unroll")                                                          \
    for (int h = 0; h < 2; ++h) {                                              \
      _Pragma("unroll")                                                        \
      for (int it = 0; it < 2; ++it) {                                         \
        const int row = h * 128 + it * 64 + r0;                                \
        const int ldst = (B_) * 32768 + h * 16384 + it * 8192 + t * 16;        \
        async_copy16(enb + (size_t)(rowA0 + row) * 512 + kb + cb,              \
                     (char*)lA + ldst);                                        \
        async_copy16(enb + (size_t)(rowB0 + row) * 512 + kb + cb,              \
                     (char*)lB + ldst);                                        \
      }                                                                        \
    }                                                                          \
  }

#define READ_AF(B_, MIBASE)                                                    \
  _Pragma("unroll")                                                            \
  for (int m = 0; m < 4; ++m) {                                                \
    const int ro = (B_) * 32768 + (wm + ((MIBASE) + m) * 16 + r15) * 128;      \
    af[m][0] = *(const bf16x8*)((const char*)lA + ro + ((0 + kq) ^ sw));       \
    af[m][1] = *(const bf16x8*)((const char*)lA + ro + ((64 + kq) ^ sw));      \
  }

#define READ_BF(B_, DST, NIBASE)                                               \
  _Pragma("unroll")                                                            \
  for (int n = 0; n < 2; ++n) {                                                \
    const int ro = (B_) * 32768 + (wn + ((NIBASE) + n) * 16 + r15) * 128;      \
    DST[n][0] = *(const bf16x8*)((const char*)lB + ro + ((0 + kq) ^ sw));      \
    DST[n][1] = *(const bf16x8*)((const char*)lB + ro + ((64 + kq) ^ sw));     \
  }

#define MFMA16(BF, MIBASE, NIBASE)                                             \
  __builtin_amdgcn_s_setprio(1);                                               \
  _Pragma("unroll")                                                            \
  for (int m = 0; m < 4; ++m)                                                  \
    _Pragma("unroll")                                                          \
    for (int n = 0; n < 2; ++n) {                                              \
      accf[(MIBASE) + m][(NIBASE) + n] =                                       \
          __builtin_amdgcn_mfma_f32_16x16x32_bf16(                             \
              af[m][0], BF[n][0], accf[(MIBASE) + m][(NIBASE) + n], 0, 0, 0);  \
      accf[(MIBASE) + m][(NIBASE) + n] =                                       \
          __builtin_amdgcn_mfma_f32_16x16x32_bf16(                             \
              af[m][1], BF[n][1], accf[(MIBASE) + m][(NIBASE) + n], 0, 0, 0);  \
    }                                                                          \
  __builtin_amdgcn_s_setprio(0);

#define WAITV0 asm volatile("s_waitcnt vmcnt(0)" ::: "memory")
#define BAR __builtin_amdgcn_s_barrier()

  bf16x8 af[4][2], bf01[2][2], bf23[2][2];

  STAGE_BATCH(0, 0);
  __syncthreads();  // drain prologue stages + label writes

  #pragma unroll
  for (int kt = 0; kt < 4; ++kt) {
    const int cur = kt & 1;
    // P0: wait own prefetch (issued a full K-step ago), sync, read, prefetch
    if (kt > 0) { WAITV0; BAR; }
    READ_AF(cur, 0);
    READ_BF(cur, bf01, 0);
    if (kt < 3) STAGE_BATCH(1 - cur, kt + 1);
    MFMA16(bf01, 0, 0);
    BAR;
    // P1
    READ_BF(cur, bf23, 2);
    MFMA16(bf23, 0, 2);
    BAR;
    // P2
    READ_AF(cur, 4);
    MFMA16(bf23, 4, 2);
    BAR;
    // P3: pure MFMA (no reads)
    MFMA16(bf01, 4, 0);
  }

  // ---- epilogue: masked accumulation ----
  // C/D layout: col = lane&15, row = (lane>>4)*4 + j  [m89/m91]
  float ps = 0.f, ns = 0.f;
  #pragma unroll
  for (int mi = 0; mi < 8; ++mi) {
    int lr[4];
    #pragma unroll
    for (int j = 0; j < 4; ++j)
      lr[j] = labA_s[wm + mi * 16 + ((lane >> 4) << 2) + j];
    #pragma unroll
    for (int ni = 0; ni < 4; ++ni) {
      const int lc = labB_s[wn + ni * 16 + r15];
      #pragma unroll
      for (int j = 0; j < 4; ++j) {
        const float s = accf[mi][ni][j];
        if (lr[j] == lc) { const float d = 1.f - s; ps += d * d; }
        else             { float d = s - 1.f; d = fmaxf(d, 0.f); ns += d * d; }
      }
    }
  }
  if (bi != bj) { ps *= 2.f; ns *= 2.f; }  // symmetry weight

  #pragma unroll
  for (int o = 32; o; o >>= 1) { ps += __shfl_down(ps, o); ns += __shfl_down(ns, o); }
  if (lane == 0) { red[wid * 2] = ps; red[wid * 2 + 1] = ns; }
  __syncthreads();
  if (t == 0) {
    float tps = 0.f, tns = 0.f;
    #pragma unroll
    for (int w = 0; w < 8; ++w) { tps += red[w * 2]; tns += red[w * 2 + 1]; }
    float2 v; v.x = tps; v.y = tns;
    parts[p] = v;
  }
}

// ---------------------------------------------------------------------------
// Kernel 3: label histogram + partial reduction + final scalar.
// ---------------------------------------------------------------------------
__global__ __launch_bounds__(1024)
void finalize_kernel(const int* __restrict__ labels,
                     const float2* __restrict__ parts,
                     float* __restrict__ out) {
  __shared__ int cnt[NUM_CLASSES];
  __shared__ float rps[16], rns[16];
  const int t = threadIdx.x;
  if (t < NUM_CLASSES) cnt[t] = 0;
  __syncthreads();
  for (int i = t; i < N_ROWS; i += 1024) atomicAdd(&cnt[labels[i]], 1);

  float ps = 0.f, ns = 0.f;
  for (int i = t; i < NWG; i += 1024) { float2 v = parts[i]; ps += v.x; ns += v.y; }
  #pragma unroll
  for (int o = 32; o; o >>= 1) { ps += __shfl_down(ps, o); ns += __shfl_down(ns, o); }
  if ((t & 63) == 0) { rps[t >> 6] = ps; rns[t >> 6] = ns; }
  __syncthreads();
  if (t == 0) {
    float tps = 0.f, tns = 0.f;
    #pragma unroll
    for (int w = 0; w < 16; ++w) { tps += rps[w]; tns += rns[w]; }
    long long pc = 0;
    for (int c = 0; c < NUM_CLASSES; ++c) pc += (long long)cnt[c] * cnt[c];
    const float fn = (float)((long long)N_ROWS * N_ROWS - pc);
    out[0] = tps / (float)pc + tns / fn;
  }
}

extern "C" void kernel_launch(void* const* d_in, const int* in_sizes, int n_in,
                              void* d_out, int out_size, void* d_ws, size_t ws_size,
                              hipStream_t stream) {
  const float* emb = (const float*)d_in[0];
  const int* labels = (const int*)d_in[1];
  float* out = (float*)d_out;

  unsigned short* en = (unsigned short*)d_ws;                          // 4 MB
  float2* parts = (float2*)((char*)d_ws + (size_t)N_ROWS * DIM * 2);   // 4.2 KB

  normalize_kernel<<<N_ROWS / 4, 256, 0, stream>>>(emb, en);
  sim_loss_kernel<<<NWG, 512, 0, stream>>>(en, labels, parts);
  finalize_kernel<<<1, 1024, 0, stream>>>(labels, parts, out);
}